// Round 2
// baseline (3056.624 us; speedup 1.0000x reference)
//
#include <hip/hip_runtime.h>

// Seq2Seq: enc-LSTM -> dec-LSTM -> vocab projection.  B=32 S=T=128 E=128 H=256 V=32000.
//
// Structure:
//  prep_kernel : pack Whh_{enc,dec} to f16x2 [phase][k-dword][gate] (coalesced reg reload),
//                convert W_out to bf16.
//  xg_kernel   : xg[p,b,t,g] = emb[token] . Wih[g,:]  (fp32 tiled GEMM w/ gather)
//  lstm_kernel : ONE 512-thread WG per batch (32 WGs). Thread t owns TWO gate rows
//                g0=t (class i/f) and g1=t+512 (class g/o) for unit j=t&255.
//                8 waves = 2 waves/SIMD -> 256-VGPR budget: 92 k-dwords/row live in TRUE
//                arch VGPRs (184 regs; the round-1 1024-thread version was capped at 128
//                and the compiler split weights into AGPRs, paying v_accvgpr_read per use).
//                Remaining 36 k-dwords/row stream from LDS as b128 quads (147 KB).
//                h (256 f16 = 128 dwords) in LDS; per-step: dot -> gact -> barrier ->
//                c/h update -> barrier. h-broadcast = 32 ds_read_b128/wave, each feeding
//                8 fdot2 (two rows). No cross-WG traffic.
//  proj_kernel : bf16 MFMA 16x16x32, 128x128 tile, BK=128, global_load_lds(16B) staging with
//                XOR-swizzle (k8' = k8 ^ (m&15)) so frag ds_read_b128 is 2-way (free) and the
//                wave-uniform-base+lane*16 constraint of global_load_lds is respected.
//
// Workspace layout (57,344,000 B):
//   xg     f32 [2*32*128][1024]                     33,554,432
//   WhhP   u32 [2][128][1024]   (f16x2 pairs)        1,048,576
//   WoutB  bf16[32000][256]                         16,384,000
//   decO   bf16[4096][256]                           2,097,152
//   (unused)                                         4,259,840

typedef _Float16 half2v __attribute__((ext_vector_type(2)));
typedef short bf16x8 __attribute__((ext_vector_type(8)));
typedef float f32x4 __attribute__((ext_vector_type(4)));

__device__ __forceinline__ unsigned short f2h_bits(float f) {
  _Float16 h = (_Float16)f;
  return __builtin_bit_cast(unsigned short, h);
}

__device__ __forceinline__ unsigned short f2bf_bits(float f) {
  unsigned u = __builtin_bit_cast(unsigned, f);
  u += 0x7fffu + ((u >> 16) & 1u);
  return (unsigned short)(u >> 16);
}

__device__ __forceinline__ float fdot2u(unsigned wu, unsigned hu, float acc) {
#if defined(__has_builtin) && __has_builtin(__builtin_amdgcn_fdot2)
  return __builtin_amdgcn_fdot2(__builtin_bit_cast(half2v, wu),
                                __builtin_bit_cast(half2v, hu), acc, false);
#else
  half2v a = __builtin_bit_cast(half2v, wu);
  half2v b = __builtin_bit_cast(half2v, hu);
  return acc + (float)a[0] * (float)b[0] + (float)a[1] * (float)b[1];
#endif
}

__device__ __forceinline__ float tanh_fast(float x) {
  float e = __expf(2.f * x);
  return 1.f - 2.f / (e + 1.f);
}

__device__ __forceinline__ float sigmoid_fast(float x) {
  return 1.f / (1.f + __expf(-x));
}

__device__ __forceinline__ void gload_lds16(const void* g, void* l) {
#if defined(__has_builtin) && __has_builtin(__builtin_amdgcn_global_load_lds)
  __builtin_amdgcn_global_load_lds(
      (const __attribute__((address_space(1))) void*)g,
      (__attribute__((address_space(3))) void*)l, 16, 0, 0);
#else
  *(uint4*)l = *(const uint4*)g;
#endif
}

// ---------------------------------------------------------------- prep ----
__global__ void prep_kernel(const float* __restrict__ WhhE, const float* __restrict__ WhhD,
                            const float* __restrict__ Wout,
                            unsigned* __restrict__ WhhP, unsigned short* __restrict__ WoutB) {
  int i = blockIdx.x * blockDim.x + threadIdx.x;
  int stride = gridDim.x * blockDim.x;
  // Whh pack: layout [p][d][g], d = k-pair dword 0..127, g = gate row 0..1023
  for (int idx = i; idx < 262144; idx += stride) {
    int p = idx >> 17;
    int rem = idx & 131071;
    int d = rem >> 10;
    int g = rem & 1023;
    const float* W = p ? WhhD : WhhE;
    float a = W[g * 256 + 2 * d];
    float b = W[g * 256 + 2 * d + 1];
    WhhP[idx] = (unsigned)f2h_bits(a) | ((unsigned)f2h_bits(b) << 16);
  }
  for (int idx = i; idx < 8192000; idx += stride) {
    WoutB[idx] = f2bf_bits(Wout[idx]);
  }
}

// ------------------------------------------------------------------ xg ----
// xg[m][n] = sum_e emb[tok(m)][e] * Wih[n][e],  m = p*4096 + b*128 + t (8192 rows), n = 0..1023
__global__ __launch_bounds__(256, 2) void xg_kernel(
    const int* __restrict__ x, const int* __restrict__ y,
    const float* __restrict__ enc_emb, const float* __restrict__ dec_emb,
    const float* __restrict__ Wih_enc, const float* __restrict__ Wih_dec,
    float* __restrict__ xg) {
  __shared__ float Al[64][132];
  __shared__ float Bl[64][132];
  __shared__ int tok[64];
  const int nb = blockIdx.x;     // 0..15  (n tile)
  const int mbb = blockIdx.y;    // 0..127 (m tile)
  const int m0 = mbb * 64;
  const int p = mbb >> 6;
  const int tid = threadIdx.x;

  if (tid < 64) {
    int mloc = (m0 + tid) & 4095;  // index into x/y flat [32*128]
    tok[tid] = p ? y[mloc] : x[mloc];
  }
  __syncthreads();

  const float* emb = p ? dec_emb : enc_emb;
  const float* Wih = p ? Wih_dec : Wih_enc;
  {
    int ri = tid & 63, seg = tid >> 6;  // 64 rows x 4 segments of 32 floats
    const float* er = emb + (size_t)tok[ri] * 128 + seg * 32;
    const float* wr = Wih + (size_t)(nb * 64 + ri) * 128 + seg * 32;
#pragma unroll
    for (int c = 0; c < 8; ++c) {
      *(float4*)&Al[ri][seg * 32 + c * 4] = *(const float4*)&er[c * 4];
      *(float4*)&Bl[ri][seg * 32 + c * 4] = *(const float4*)&wr[c * 4];
    }
  }
  __syncthreads();

  const int tx = tid & 15, ty = tid >> 4;
  float acc[4][4];
#pragma unroll
  for (int mm = 0; mm < 4; ++mm)
#pragma unroll
    for (int nn = 0; nn < 4; ++nn) acc[mm][nn] = 0.f;

  for (int k4 = 0; k4 < 32; ++k4) {
    float4 av[4], bv[4];
#pragma unroll
    for (int mm = 0; mm < 4; ++mm) av[mm] = *(const float4*)&Al[mm * 16 + ty][k4 * 4];
#pragma unroll
    for (int nn = 0; nn < 4; ++nn) bv[nn] = *(const float4*)&Bl[nn * 16 + tx][k4 * 4];
#pragma unroll
    for (int mm = 0; mm < 4; ++mm)
#pragma unroll
      for (int nn = 0; nn < 4; ++nn) {
        acc[mm][nn] = fmaf(av[mm].x, bv[nn].x, acc[mm][nn]);
        acc[mm][nn] = fmaf(av[mm].y, bv[nn].y, acc[mm][nn]);
        acc[mm][nn] = fmaf(av[mm].z, bv[nn].z, acc[mm][nn]);
        acc[mm][nn] = fmaf(av[mm].w, bv[nn].w, acc[mm][nn]);
      }
  }
#pragma unroll
  for (int mm = 0; mm < 4; ++mm)
#pragma unroll
    for (int nn = 0; nn < 4; ++nn)
      xg[(size_t)(m0 + mm * 16 + ty) * 1024 + nb * 64 + nn * 16 + tx] = acc[mm][nn];
}

// ---------------------------------------------------------------- lstm ----
// One 512-thread WG per batch. Thread t owns gate rows g0=t and g1=t+512.
// q0 = t>>8 in {0:i, 1:f}; row1 class = q0+2 in {2:g, 3:o}; unit j = t&255.
// Weights: k-dwords 0..91 per row in arch VGPRs (w0[92], w1[92]); k-dwords 92..127
// in LDS as b128 quads WL[9][1024][4] (thread-private columns, no staging barrier).
__global__ __launch_bounds__(512, 2) void lstm_kernel(
    const float* __restrict__ xg, const unsigned* __restrict__ WhhP,
    const float* __restrict__ bih_enc, const float* __restrict__ bhh_enc,
    const float* __restrict__ bih_dec, const float* __restrict__ bhh_dec,
    unsigned short* __restrict__ decO) {   // bf16 [4096][256]
  const int b = blockIdx.x;   // batch 0..31
  const int t = threadIdx.x;  // 0..511
  const int g0 = t;
  const int g1 = t + 512;
  const int q0 = t >> 8;      // wave-uniform (waves 0-3 -> 0, waves 4-7 -> 1)
  const int j = t & 255;      // unit

  __shared__ __align__(16) unsigned h2[128];     // full h as f16x2 pairs (256 f16)
  __shared__ float gact[4][256];                 // 4 KB
  __shared__ __align__(16) unsigned WL[9 * 1024 * 4];  // quads cc=0..8 -> k-dwords 92+4cc.. ; 147,456 B

  if (t < 128) h2[t] = 0u;
  float c_r = 0.f;  // cell state, owned by t<256 threads (unit j=t)
  __syncthreads();

  unsigned w0[92], w1[92];  // arch-VGPR-resident f16x2 weight rows (k-pairs 0..91)
  float bias0 = 0.f, bias1 = 0.f;

  // xg row pointer + prefetch for s=0
  const float* xp = xg + (size_t)(b << 7) * 1024;
  float xv0 = xp[g0];
  float xv1 = xp[g1];

  for (int s = 0; s < 256; ++s) {
    const int p = s >> 7;
    const int tt = s & 127;

    if (tt == 0) {  // phase start: (re)load weights + bias
      const unsigned* base = WhhP + (p << 17);
#pragma unroll
      for (int d = 0; d < 92; ++d) {
        w0[d] = base[(d << 10) + g0];
        w1[d] = base[(d << 10) + g1];
      }
#pragma unroll
      for (int cc = 0; cc < 9; ++cc) {
        uint4 qa, qb;
        qa.x = base[((92 + 4 * cc + 0) << 10) + g0];
        qa.y = base[((92 + 4 * cc + 1) << 10) + g0];
        qa.z = base[((92 + 4 * cc + 2) << 10) + g0];
        qa.w = base[((92 + 4 * cc + 3) << 10) + g0];
        qb.x = base[((92 + 4 * cc + 0) << 10) + g1];
        qb.y = base[((92 + 4 * cc + 1) << 10) + g1];
        qb.z = base[((92 + 4 * cc + 2) << 10) + g1];
        qb.w = base[((92 + 4 * cc + 3) << 10) + g1];
        *(uint4*)&WL[((cc << 10) + g0) << 2] = qa;
        *(uint4*)&WL[((cc << 10) + g1) << 2] = qb;
      }
      bias0 = p ? (bih_dec[g0] + bhh_dec[g0]) : (bih_enc[g0] + bhh_enc[g0]);
      bias1 = p ? (bih_dec[g1] + bhh_dec[g1]) : (bih_enc[g1] + bhh_enc[g1]);
    }

    const float x0 = xv0, x1 = xv1;
    if (s < 255) {  // prefetch next step's xg (rows are sequential; phase edge jumps)
      xp += (tt == 127) ? 3969 * 1024 : 1024;
      xv0 = xp[g0];
      xv1 = xp[g1];
    }

    // dot over K=256: h2 reads are wave-uniform b128 broadcasts; each feeds 8 fdot2
    float a00 = 0.f, a01 = 0.f, a02 = 0.f, a03 = 0.f;
    float a10 = 0.f, a11 = 0.f, a12 = 0.f, a13 = 0.f;
#pragma unroll
    for (int c = 0; c < 23; ++c) {
      const uint4 hv = *(const uint4*)&h2[c << 2];
      a00 = fdot2u(w0[4 * c + 0], hv.x, a00);
      a01 = fdot2u(w0[4 * c + 1], hv.y, a01);
      a02 = fdot2u(w0[4 * c + 2], hv.z, a02);
      a03 = fdot2u(w0[4 * c + 3], hv.w, a03);
      a10 = fdot2u(w1[4 * c + 0], hv.x, a10);
      a11 = fdot2u(w1[4 * c + 1], hv.y, a11);
      a12 = fdot2u(w1[4 * c + 2], hv.z, a12);
      a13 = fdot2u(w1[4 * c + 3], hv.w, a13);
    }
#pragma unroll
    for (int c = 23; c < 32; ++c) {
      const uint4 hv = *(const uint4*)&h2[c << 2];
      const uint4 qa = *(const uint4*)&WL[(((c - 23) << 10) + g0) << 2];
      const uint4 qb = *(const uint4*)&WL[(((c - 23) << 10) + g1) << 2];
      a00 = fdot2u(qa.x, hv.x, a00);
      a01 = fdot2u(qa.y, hv.y, a01);
      a02 = fdot2u(qa.z, hv.z, a02);
      a03 = fdot2u(qa.w, hv.w, a03);
      a10 = fdot2u(qb.x, hv.x, a10);
      a11 = fdot2u(qb.y, hv.y, a11);
      a12 = fdot2u(qb.z, hv.z, a12);
      a13 = fdot2u(qb.w, hv.w, a13);
    }
    const float acc0 = bias0 + x0 + ((a00 + a01) + (a02 + a03));
    const float acc1 = bias1 + x1 + ((a10 + a11) + (a12 + a13));

    // activations: row0 class in {i,f} -> sigmoid; row1 class = q0+2 -> {g: tanh, o: sigmoid}
    const float act0 = sigmoid_fast(acc0);
    const float act1 = (q0 == 0) ? tanh_fast(acc1) : sigmoid_fast(acc1);  // wave-uniform
    gact[q0][j] = act0;
    gact[q0 + 2][j] = act1;
    __syncthreads();

    if (t < 256) {  // unit j=t update (waves 0..3 fully active -> shfl safe)
      const float iv = gact[0][t];
      const float fv = gact[1][t];
      const float gv = gact[2][t];
      const float ov = gact[3][t];
      c_r = fv * c_r + iv * gv;
      const float hh = ov * tanh_fast(c_r);
      if (p) decO[(size_t)((b << 7) + tt) * 256 + t] = f2bf_bits(hh);
      const float hn = __shfl_down(hh, 1, 64);
      if (!(t & 1))
        h2[t >> 1] = (unsigned)f2h_bits(hh) | ((unsigned)f2h_bits(hn) << 16);
    }
    __syncthreads();  // h2 update visible before next step's dot
  }
}

// ---------------------------------------------------------------- proj ----
// out[m][n] = sum_k A[m][k]*Bw[n][k] + bias[n];  M=4096 N=32000 K=256, bf16 MFMA
__global__ __launch_bounds__(256, 2) void proj_kernel(
    const unsigned short* __restrict__ A,   // decO bf16 [4096][256]
    const unsigned short* __restrict__ Bw,  // WoutB bf16 [32000][256]
    const float* __restrict__ bias, float* __restrict__ out) {
  __shared__ unsigned short Al[128 * 128];
  __shared__ unsigned short Bl[128 * 128];
  const int mb = blockIdx.x;  // 0..31
  const int nb = blockIdx.y;  // 0..249
  const int tid = threadIdx.x;
  const int wv = tid >> 6, ln = tid & 63;
  const int wm = wv & 1, wn = wv >> 1;  // 2x2 waves, each 64x64
  const int l16 = ln & 15, lq = ln >> 4;

  f32x4 acc[4][4] = {};

  for (int kc = 0; kc < 2; ++kc) {
    // stage A then B: slot st -> (m = st>>4, k8 = st&15); source k8 swizzled by m&15
#pragma unroll
    for (int it = 0; it < 8; ++it) {
      int st = it * 256 + tid;
      int m = st >> 4, k8 = st & 15;
      const unsigned short* gp =
          A + (size_t)(mb * 128 + m) * 256 + kc * 128 + ((k8 ^ (m & 15)) << 3);
      gload_lds16(gp, &Al[st << 3]);
    }
#pragma unroll
    for (int it = 0; it < 8; ++it) {
      int st = it * 256 + tid;
      int m = st >> 4, k8 = st & 15;
      const unsigned short* gp =
          Bw + (size_t)(nb * 128 + m) * 256 + kc * 128 + ((k8 ^ (m & 15)) << 3);
      gload_lds16(gp, &Bl[st << 3]);
    }
    asm volatile("s_waitcnt vmcnt(0)" ::: "memory");
    __syncthreads();

#pragma unroll
    for (int ks = 0; ks < 4; ++ks) {
      const int k8 = (ks << 2) + lq;
      bf16x8 af[4], bf[4];
#pragma unroll
      for (int mt = 0; mt < 4; ++mt) {
        int m = (wm << 6) + (mt << 4) + l16;
        af[mt] = *(const bf16x8*)&Al[(m << 7) + ((k8 ^ (m & 15)) << 3)];
      }
#pragma unroll
      for (int nt = 0; nt < 4; ++nt) {
        int n = (wn << 6) + (nt << 4) + l16;
        bf[nt] = *(const bf16x8*)&Bl[(n << 7) + ((k8 ^ (n & 15)) << 3)];
      }
#pragma unroll
      for (int mt = 0; mt < 4; ++mt)
#pragma unroll
        for (int nt = 0; nt < 4; ++nt)
          acc[mt][nt] = __builtin_amdgcn_mfma_f32_16x16x32_bf16(af[mt], bf[nt],
                                                                acc[mt][nt], 0, 0, 0);
    }
    __syncthreads();
  }

  // epilogue: D row = (lq*4 + rr) within 16 (M), col = l16 (N)
#pragma unroll
  for (int nt = 0; nt < 4; ++nt) {
    const int gcol = nb * 128 + (wn << 6) + (nt << 4) + l16;
    const float bs = bias[gcol];
#pragma unroll
    for (int mt = 0; mt < 4; ++mt) {
      const int grow0 = mb * 128 + (wm << 6) + (mt << 4) + (lq << 2);
#pragma unroll
      for (int rr = 0; rr < 4; ++rr)
        out[(size_t)(grow0 + rr) * 32000 + gcol] = acc[mt][nt][rr] + bs;
    }
  }
}

// -------------------------------------------------------------- launch ----
extern "C" void kernel_launch(void* const* d_in, const int* in_sizes, int n_in,
                              void* d_out, int out_size, void* d_ws, size_t ws_size,
                              hipStream_t stream) {
  const int* x = (const int*)d_in[0];
  const int* y = (const int*)d_in[1];
  const float* enc_emb = (const float*)d_in[2];
  const float* dec_emb = (const float*)d_in[3];
  const float* Wih_enc = (const float*)d_in[4];
  const float* Whh_enc = (const float*)d_in[5];
  const float* bih_enc = (const float*)d_in[6];
  const float* bhh_enc = (const float*)d_in[7];
  const float* Wih_dec = (const float*)d_in[8];
  const float* Whh_dec = (const float*)d_in[9];
  const float* bih_dec = (const float*)d_in[10];
  const float* bhh_dec = (const float*)d_in[11];
  const float* W_out = (const float*)d_in[12];
  const float* b_out = (const float*)d_in[13];

  char* ws = (char*)d_ws;
  float* xg = (float*)ws;                                       // 33,554,432
  unsigned* WhhP = (unsigned*)(ws + 33554432);                  //  1,048,576
  unsigned short* WoutB = (unsigned short*)(ws + 34603008);     // 16,384,000
  unsigned short* decO = (unsigned short*)(ws + 50987008);      //  2,097,152
  if (ws_size < 57344000) return;  // insufficient workspace (would corrupt)

  prep_kernel<<<4096, 256, 0, stream>>>(Whh_enc, Whh_dec, W_out, WhhP, WoutB);
  xg_kernel<<<dim3(16, 128), 256, 0, stream>>>(x, y, enc_emb, dec_emb, Wih_enc, Wih_dec, xg);
  lstm_kernel<<<32, 512, 0, stream>>>(xg, WhhP, bih_enc, bhh_enc, bih_dec, bhh_dec, decO);
  proj_kernel<<<dim3(32, 250), 256, 0, stream>>>(decO, WoutB, b_out, (float*)d_out);
}

// Round 3
// 3051.042 us; speedup vs baseline: 1.0018x; 1.0018x over previous
//
#include <hip/hip_runtime.h>

// Seq2Seq: enc-LSTM -> dec-LSTM -> vocab projection.  B=32 S=T=128 E=128 H=256 V=32000.
//
// Structure:
//  prep_kernel : pack Whh_{enc,dec} to f16x2 [phase][k-dword][gate] (coalesced reg reload),
//                convert W_out to bf16.
//  xg_kernel   : xg[p,b,t,g] = emb[token] . Wih[g,:]  (fp32 tiled GEMM w/ gather)
//  lstm_kernel : ONE 512-thread WG per batch (32 WGs). Thread t owns TWO gate rows
//                g0=t and g1=t+512 for unit j=t&255.
//                amdgpu_waves_per_eu(2,2) pins occupancy at 2 waves/SIMD -> 256-VGPR
//                budget AND removes the compiler's incentive to shrink to 128 regs for
//                2 blocks/CU (round-2 failure: it targeted 4 waves/SIMD, capped at 128,
//                spilled ~66 dwords to scratch -> 4x slowdown, WRITE_SIZE +7.6MB).
//                92 k-dwords/row in arch VGPRs (184 regs, direct v_dot2 operands);
//                36 k-dwords/row stream from LDS as b128 quads (147 KB = LDS cap).
//                h (256 f16 = 128 dwords) in LDS; per-step: dot -> gact -> barrier ->
//                c/h update -> barrier. h-broadcast = 32 uniform ds_read_b128/wave,
//                each feeding 8 fdot2 (two rows). No cross-WG traffic.
//  proj_kernel : bf16 MFMA 16x16x32, 128x128 tile, BK=128, global_load_lds(16B) staging with
//                XOR-swizzle (k8' = k8 ^ (m&15)) so frag ds_read_b128 is 2-way (free) and the
//                wave-uniform-base+lane*16 constraint of global_load_lds is respected.
//
// Workspace layout (57,344,000 B):
//   xg     f32 [2*32*128][1024]                     33,554,432
//   WhhP   u32 [2][128][1024]   (f16x2 pairs)        1,048,576
//   WoutB  bf16[32000][256]                         16,384,000
//   decO   bf16[4096][256]                           2,097,152
//   (unused)                                         4,259,840

typedef _Float16 half2v __attribute__((ext_vector_type(2)));
typedef short bf16x8 __attribute__((ext_vector_type(8)));
typedef float f32x4 __attribute__((ext_vector_type(4)));

__device__ __forceinline__ unsigned short f2h_bits(float f) {
  _Float16 h = (_Float16)f;
  return __builtin_bit_cast(unsigned short, h);
}

__device__ __forceinline__ unsigned short f2bf_bits(float f) {
  unsigned u = __builtin_bit_cast(unsigned, f);
  u += 0x7fffu + ((u >> 16) & 1u);
  return (unsigned short)(u >> 16);
}

__device__ __forceinline__ float fdot2u(unsigned wu, unsigned hu, float acc) {
#if defined(__has_builtin) && __has_builtin(__builtin_amdgcn_fdot2)
  return __builtin_amdgcn_fdot2(__builtin_bit_cast(half2v, wu),
                                __builtin_bit_cast(half2v, hu), acc, false);
#else
  half2v a = __builtin_bit_cast(half2v, wu);
  half2v b = __builtin_bit_cast(half2v, hu);
  return acc + (float)a[0] * (float)b[0] + (float)a[1] * (float)b[1];
#endif
}

__device__ __forceinline__ float tanh_fast(float x) {
  float e = __expf(2.f * x);
  return 1.f - 2.f / (e + 1.f);
}

__device__ __forceinline__ float sigmoid_fast(float x) {
  return 1.f / (1.f + __expf(-x));
}

__device__ __forceinline__ void gload_lds16(const void* g, void* l) {
#if defined(__has_builtin) && __has_builtin(__builtin_amdgcn_global_load_lds)
  __builtin_amdgcn_global_load_lds(
      (const __attribute__((address_space(1))) void*)g,
      (__attribute__((address_space(3))) void*)l, 16, 0, 0);
#else
  *(uint4*)l = *(const uint4*)g;
#endif
}

// ---------------------------------------------------------------- prep ----
__global__ void prep_kernel(const float* __restrict__ WhhE, const float* __restrict__ WhhD,
                            const float* __restrict__ Wout,
                            unsigned* __restrict__ WhhP, unsigned short* __restrict__ WoutB) {
  int i = blockIdx.x * blockDim.x + threadIdx.x;
  int stride = gridDim.x * blockDim.x;
  // Whh pack: layout [p][d][g], d = k-pair dword 0..127, g = gate row 0..1023
  for (int idx = i; idx < 262144; idx += stride) {
    int p = idx >> 17;
    int rem = idx & 131071;
    int d = rem >> 10;
    int g = rem & 1023;
    const float* W = p ? WhhD : WhhE;
    float a = W[g * 256 + 2 * d];
    float b = W[g * 256 + 2 * d + 1];
    WhhP[idx] = (unsigned)f2h_bits(a) | ((unsigned)f2h_bits(b) << 16);
  }
  for (int idx = i; idx < 8192000; idx += stride) {
    WoutB[idx] = f2bf_bits(Wout[idx]);
  }
}

// ------------------------------------------------------------------ xg ----
// xg[m][n] = sum_e emb[tok(m)][e] * Wih[n][e],  m = p*4096 + b*128 + t (8192 rows), n = 0..1023
__global__ __launch_bounds__(256, 2) void xg_kernel(
    const int* __restrict__ x, const int* __restrict__ y,
    const float* __restrict__ enc_emb, const float* __restrict__ dec_emb,
    const float* __restrict__ Wih_enc, const float* __restrict__ Wih_dec,
    float* __restrict__ xg) {
  __shared__ float Al[64][132];
  __shared__ float Bl[64][132];
  __shared__ int tok[64];
  const int nb = blockIdx.x;     // 0..15  (n tile)
  const int mbb = blockIdx.y;    // 0..127 (m tile)
  const int m0 = mbb * 64;
  const int p = mbb >> 6;
  const int tid = threadIdx.x;

  if (tid < 64) {
    int mloc = (m0 + tid) & 4095;  // index into x/y flat [32*128]
    tok[tid] = p ? y[mloc] : x[mloc];
  }
  __syncthreads();

  const float* emb = p ? dec_emb : enc_emb;
  const float* Wih = p ? Wih_dec : Wih_enc;
  {
    int ri = tid & 63, seg = tid >> 6;  // 64 rows x 4 segments of 32 floats
    const float* er = emb + (size_t)tok[ri] * 128 + seg * 32;
    const float* wr = Wih + (size_t)(nb * 64 + ri) * 128 + seg * 32;
#pragma unroll
    for (int c = 0; c < 8; ++c) {
      *(float4*)&Al[ri][seg * 32 + c * 4] = *(const float4*)&er[c * 4];
      *(float4*)&Bl[ri][seg * 32 + c * 4] = *(const float4*)&wr[c * 4];
    }
  }
  __syncthreads();

  const int tx = tid & 15, ty = tid >> 4;
  float acc[4][4];
#pragma unroll
  for (int mm = 0; mm < 4; ++mm)
#pragma unroll
    for (int nn = 0; nn < 4; ++nn) acc[mm][nn] = 0.f;

  for (int k4 = 0; k4 < 32; ++k4) {
    float4 av[4], bv[4];
#pragma unroll
    for (int mm = 0; mm < 4; ++mm) av[mm] = *(const float4*)&Al[mm * 16 + ty][k4 * 4];
#pragma unroll
    for (int nn = 0; nn < 4; ++nn) bv[nn] = *(const float4*)&Bl[nn * 16 + tx][k4 * 4];
#pragma unroll
    for (int mm = 0; mm < 4; ++mm)
#pragma unroll
      for (int nn = 0; nn < 4; ++nn) {
        acc[mm][nn] = fmaf(av[mm].x, bv[nn].x, acc[mm][nn]);
        acc[mm][nn] = fmaf(av[mm].y, bv[nn].y, acc[mm][nn]);
        acc[mm][nn] = fmaf(av[mm].z, bv[nn].z, acc[mm][nn]);
        acc[mm][nn] = fmaf(av[mm].w, bv[nn].w, acc[mm][nn]);
      }
  }
#pragma unroll
  for (int mm = 0; mm < 4; ++mm)
#pragma unroll
    for (int nn = 0; nn < 4; ++nn)
      xg[(size_t)(m0 + mm * 16 + ty) * 1024 + nb * 64 + nn * 16 + tx] = acc[mm][nn];
}

// ---------------------------------------------------------------- lstm ----
// One 512-thread WG per batch. Thread t owns gate rows g0=t and g1=t+512.
// q0 = t>>8 in {0:i, 1:f}; row1 class = q0+2 in {2:g, 3:o}; unit j = t&255.
// Weights: k-dwords 0..91 per row in arch VGPRs (w0[92], w1[92]); k-dwords 92..127
// in LDS as b128 quads WL[9][1024][4] (thread-private columns, no staging barrier).
// waves_per_eu(2,2): pin 2 waves/SIMD -> 256-reg budget, no occupancy-chasing spill.
__global__ __launch_bounds__(512)
__attribute__((amdgpu_waves_per_eu(2, 2))) void lstm_kernel(
    const float* __restrict__ xg, const unsigned* __restrict__ WhhP,
    const float* __restrict__ bih_enc, const float* __restrict__ bhh_enc,
    const float* __restrict__ bih_dec, const float* __restrict__ bhh_dec,
    unsigned short* __restrict__ decO) {   // bf16 [4096][256]
  const int b = blockIdx.x;   // batch 0..31
  const int t = threadIdx.x;  // 0..511
  const int g0 = t;
  const int g1 = t + 512;
  const int q0 = t >> 8;      // wave-uniform (waves 0-3 -> 0, waves 4-7 -> 1)
  const int j = t & 255;      // unit

  __shared__ __align__(16) unsigned h2[128];     // full h as f16x2 pairs (256 f16)
  __shared__ float gact[4][256];                 // 4 KB
  __shared__ __align__(16) unsigned WL[9 * 1024 * 4];  // quads cc=0..8 -> k-dwords 92+4cc.. ; 147,456 B

  if (t < 128) h2[t] = 0u;
  float c_r = 0.f;  // cell state, owned by t<256 threads (unit j=t)
  __syncthreads();

  unsigned w0[92], w1[92];  // arch-VGPR-resident f16x2 weight rows (k-pairs 0..91)
  float bias0 = 0.f, bias1 = 0.f;

  // xg row pointer + prefetch for s=0
  const float* xp = xg + (size_t)(b << 7) * 1024;
  float xv0 = xp[g0];
  float xv1 = xp[g1];

  for (int s = 0; s < 256; ++s) {
    const int p = s >> 7;
    const int tt = s & 127;

    if (tt == 0) {  // phase start: (re)load weights + bias (runs twice; time-negligible)
      const unsigned* base = WhhP + (p << 17);
#pragma unroll
      for (int d = 0; d < 92; ++d) {
        w0[d] = base[(d << 10) + g0];
        w1[d] = base[(d << 10) + g1];
      }
      // LDS slice: thread-private column, quad layout [cc][gate][4]; dword stores keep
      // staging temporaries minimal (regalloc margin).
#pragma unroll
      for (int cc = 0; cc < 9; ++cc) {
#pragma unroll
        for (int e = 0; e < 4; ++e) {
          WL[(((cc << 10) + g0) << 2) + e] = base[((92 + 4 * cc + e) << 10) + g0];
          WL[(((cc << 10) + g1) << 2) + e] = base[((92 + 4 * cc + e) << 10) + g1];
        }
      }
      bias0 = p ? (bih_dec[g0] + bhh_dec[g0]) : (bih_enc[g0] + bhh_enc[g0]);
      bias1 = p ? (bih_dec[g1] + bhh_dec[g1]) : (bih_enc[g1] + bhh_enc[g1]);
    }

    const float x0 = xv0, x1 = xv1;
    if (s < 255) {  // prefetch next step's xg (rows are sequential; phase edge jumps)
      xp += (tt == 127) ? 3969 * 1024 : 1024;
      xv0 = xp[g0];
      xv1 = xp[g1];
    }

    // dot over K=256: h2 reads are wave-uniform b128 broadcasts; each feeds 8 fdot2
    float a00 = 0.f, a01 = 0.f, a02 = 0.f, a03 = 0.f;
    float a10 = 0.f, a11 = 0.f, a12 = 0.f, a13 = 0.f;
#pragma unroll
    for (int c = 0; c < 23; ++c) {
      const uint4 hv = *(const uint4*)&h2[c << 2];
      a00 = fdot2u(w0[4 * c + 0], hv.x, a00);
      a01 = fdot2u(w0[4 * c + 1], hv.y, a01);
      a02 = fdot2u(w0[4 * c + 2], hv.z, a02);
      a03 = fdot2u(w0[4 * c + 3], hv.w, a03);
      a10 = fdot2u(w1[4 * c + 0], hv.x, a10);
      a11 = fdot2u(w1[4 * c + 1], hv.y, a11);
      a12 = fdot2u(w1[4 * c + 2], hv.z, a12);
      a13 = fdot2u(w1[4 * c + 3], hv.w, a13);
    }
#pragma unroll
    for (int c = 23; c < 32; ++c) {
      const uint4 hv = *(const uint4*)&h2[c << 2];
      const uint4 qa = *(const uint4*)&WL[(((c - 23) << 10) + g0) << 2];
      const uint4 qb = *(const uint4*)&WL[(((c - 23) << 10) + g1) << 2];
      a00 = fdot2u(qa.x, hv.x, a00);
      a01 = fdot2u(qa.y, hv.y, a01);
      a02 = fdot2u(qa.z, hv.z, a02);
      a03 = fdot2u(qa.w, hv.w, a03);
      a10 = fdot2u(qb.x, hv.x, a10);
      a11 = fdot2u(qb.y, hv.y, a11);
      a12 = fdot2u(qb.z, hv.z, a12);
      a13 = fdot2u(qb.w, hv.w, a13);
    }
    const float acc0 = bias0 + x0 + ((a00 + a01) + (a02 + a03));
    const float acc1 = bias1 + x1 + ((a10 + a11) + (a12 + a13));

    // activations: row0 class in {i,f} -> sigmoid; row1 class = q0+2 -> {g: tanh, o: sigmoid}
    const float act0 = sigmoid_fast(acc0);
    const float act1 = (q0 == 0) ? tanh_fast(acc1) : sigmoid_fast(acc1);  // wave-uniform
    gact[q0][j] = act0;
    gact[q0 + 2][j] = act1;
    __syncthreads();

    if (t < 256) {  // unit j=t update (waves 0..3 fully active -> shfl safe)
      const float iv = gact[0][t];
      const float fv = gact[1][t];
      const float gv = gact[2][t];
      const float ov = gact[3][t];
      c_r = fv * c_r + iv * gv;
      const float hh = ov * tanh_fast(c_r);
      if (p) decO[(size_t)((b << 7) + tt) * 256 + t] = f2bf_bits(hh);
      const float hn = __shfl_down(hh, 1, 64);
      if (!(t & 1))
        h2[t >> 1] = (unsigned)f2h_bits(hh) | ((unsigned)f2h_bits(hn) << 16);
    }
    __syncthreads();  // h2 update visible before next step's dot
  }
}

// ---------------------------------------------------------------- proj ----
// out[m][n] = sum_k A[m][k]*Bw[n][k] + bias[n];  M=4096 N=32000 K=256, bf16 MFMA
__global__ __launch_bounds__(256, 2) void proj_kernel(
    const unsigned short* __restrict__ A,   // decO bf16 [4096][256]
    const unsigned short* __restrict__ Bw,  // WoutB bf16 [32000][256]
    const float* __restrict__ bias, float* __restrict__ out) {
  __shared__ unsigned short Al[128 * 128];
  __shared__ unsigned short Bl[128 * 128];
  const int mb = blockIdx.x;  // 0..31
  const int nb = blockIdx.y;  // 0..249
  const int tid = threadIdx.x;
  const int wv = tid >> 6, ln = tid & 63;
  const int wm = wv & 1, wn = wv >> 1;  // 2x2 waves, each 64x64
  const int l16 = ln & 15, lq = ln >> 4;

  f32x4 acc[4][4] = {};

  for (int kc = 0; kc < 2; ++kc) {
    // stage A then B: slot st -> (m = st>>4, k8 = st&15); source k8 swizzled by m&15
#pragma unroll
    for (int it = 0; it < 8; ++it) {
      int st = it * 256 + tid;
      int m = st >> 4, k8 = st & 15;
      const unsigned short* gp =
          A + (size_t)(mb * 128 + m) * 256 + kc * 128 + ((k8 ^ (m & 15)) << 3);
      gload_lds16(gp, &Al[st << 3]);
    }
#pragma unroll
    for (int it = 0; it < 8; ++it) {
      int st = it * 256 + tid;
      int m = st >> 4, k8 = st & 15;
      const unsigned short* gp =
          Bw + (size_t)(nb * 128 + m) * 256 + kc * 128 + ((k8 ^ (m & 15)) << 3);
      gload_lds16(gp, &Bl[st << 3]);
    }
    asm volatile("s_waitcnt vmcnt(0)" ::: "memory");
    __syncthreads();

#pragma unroll
    for (int ks = 0; ks < 4; ++ks) {
      const int k8 = (ks << 2) + lq;
      bf16x8 af[4], bf[4];
#pragma unroll
      for (int mt = 0; mt < 4; ++mt) {
        int m = (wm << 6) + (mt << 4) + l16;
        af[mt] = *(const bf16x8*)&Al[(m << 7) + ((k8 ^ (m & 15)) << 3)];
      }
#pragma unroll
      for (int nt = 0; nt < 4; ++nt) {
        int n = (wn << 6) + (nt << 4) + l16;
        bf[nt] = *(const bf16x8*)&Bl[(n << 7) + ((k8 ^ (n & 15)) << 3)];
      }
#pragma unroll
      for (int mt = 0; mt < 4; ++mt)
#pragma unroll
        for (int nt = 0; nt < 4; ++nt)
          acc[mt][nt] = __builtin_amdgcn_mfma_f32_16x16x32_bf16(af[mt], bf[nt],
                                                                acc[mt][nt], 0, 0, 0);
    }
    __syncthreads();
  }

  // epilogue: D row = (lq*4 + rr) within 16 (M), col = l16 (N)
#pragma unroll
  for (int nt = 0; nt < 4; ++nt) {
    const int gcol = nb * 128 + (wn << 6) + (nt << 4) + l16;
    const float bs = bias[gcol];
#pragma unroll
    for (int mt = 0; mt < 4; ++mt) {
      const int grow0 = mb * 128 + (wm << 6) + (mt << 4) + (lq << 2);
#pragma unroll
      for (int rr = 0; rr < 4; ++rr)
        out[(size_t)(grow0 + rr) * 32000 + gcol] = acc[mt][nt][rr] + bs;
    }
  }
}

// -------------------------------------------------------------- launch ----
extern "C" void kernel_launch(void* const* d_in, const int* in_sizes, int n_in,
                              void* d_out, int out_size, void* d_ws, size_t ws_size,
                              hipStream_t stream) {
  const int* x = (const int*)d_in[0];
  const int* y = (const int*)d_in[1];
  const float* enc_emb = (const float*)d_in[2];
  const float* dec_emb = (const float*)d_in[3];
  const float* Wih_enc = (const float*)d_in[4];
  const float* Whh_enc = (const float*)d_in[5];
  const float* bih_enc = (const float*)d_in[6];
  const float* bhh_enc = (const float*)d_in[7];
  const float* Wih_dec = (const float*)d_in[8];
  const float* Whh_dec = (const float*)d_in[9];
  const float* bih_dec = (const float*)d_in[10];
  const float* bhh_dec = (const float*)d_in[11];
  const float* W_out = (const float*)d_in[12];
  const float* b_out = (const float*)d_in[13];

  char* ws = (char*)d_ws;
  float* xg = (float*)ws;                                       // 33,554,432
  unsigned* WhhP = (unsigned*)(ws + 33554432);                  //  1,048,576
  unsigned short* WoutB = (unsigned short*)(ws + 34603008);     // 16,384,000
  unsigned short* decO = (unsigned short*)(ws + 50987008);      //  2,097,152
  if (ws_size < 57344000) return;  // insufficient workspace (would corrupt)

  prep_kernel<<<4096, 256, 0, stream>>>(Whh_enc, Whh_dec, W_out, WhhP, WoutB);
  xg_kernel<<<dim3(16, 128), 256, 0, stream>>>(x, y, enc_emb, dec_emb, Wih_enc, Wih_dec, xg);
  lstm_kernel<<<32, 512, 0, stream>>>(xg, WhhP, bih_enc, bhh_enc, bih_dec, bhh_dec, decO);
  proj_kernel<<<dim3(32, 250), 256, 0, stream>>>(decO, WoutB, b_out, (float*)d_out);
}

// Round 4
// 1282.358 us; speedup vs baseline: 2.3836x; 2.3792x over previous
//
#include <hip/hip_runtime.h>

// Seq2Seq: enc-LSTM -> dec-LSTM -> vocab projection.  B=32 S=T=128 E=128 H=256 V=32000.
//
// Structure:
//  prep_kernel : pack Whh_{enc,dec} to f16x2 [phase][k-dword][gate], convert W_out to bf16.
//  xg_kernel   : xg[p,b,t,g] = emb[token] . Wih[g,:]  (fp32 tiled GEMM w/ gather)
//  lstm_kernel : ROUND-1 VERBATIM (measured 601 us). 1024 threads/WG, 1 WG/batch, weights
//                92 dwords reg/AGPR + 36 dwords LDS. Rounds 2-3 proved the 512-thread/
//                256-VGPR variant cannot be realized (compiler caps at 128 arch VGPRs and
//                spills to scratch; waves_per_eu(2,2) ignored). Do not revisit.
//  proj_kernel : REWRITTEN for skinny-K (K=256) + huge output (524 MB f32):
//                N-strip persistent kernel. 500 WGs x 64 vocab rows. B-strip staged to LDS
//                once, B-fragments hoisted to 64 VGPRs (no repeated B LDS reads). M-loop:
//                128 chunks x 32 rows, double-buffered A staging (2x16 KB) with counted
//                s_waitcnt vmcnt(8) (the 8 output stores of the current chunk may stay in
//                flight; only the 4 A gload_lds are drained). LDS 64 KB -> 2 WG/CU.
//                Old proj staged 64 KB per 128x128 tile with vmcnt(0) x2 and re-read B
//                for every mb -> staging-latency-bound (~500 us of the fixed 678 us blob).
//
// Workspace layout (57,344,000 B):
//   xg     f32 [2*32*128][1024]                     33,554,432
//   WhhP   u32 [2][128][1024]   (f16x2 pairs)        1,048,576
//   WoutB  bf16[32000][256]                         16,384,000
//   decO   bf16[4096][256]                           2,097,152
//   (unused)                                         4,259,840

typedef _Float16 half2v __attribute__((ext_vector_type(2)));
typedef short bf16x8 __attribute__((ext_vector_type(8)));
typedef float f32x4 __attribute__((ext_vector_type(4)));

__device__ __forceinline__ unsigned short f2h_bits(float f) {
  _Float16 h = (_Float16)f;
  return __builtin_bit_cast(unsigned short, h);
}

__device__ __forceinline__ unsigned short f2bf_bits(float f) {
  unsigned u = __builtin_bit_cast(unsigned, f);
  u += 0x7fffu + ((u >> 16) & 1u);
  return (unsigned short)(u >> 16);
}

__device__ __forceinline__ float fdot2u(unsigned wu, unsigned hu, float acc) {
#if defined(__has_builtin) && __has_builtin(__builtin_amdgcn_fdot2)
  return __builtin_amdgcn_fdot2(__builtin_bit_cast(half2v, wu),
                                __builtin_bit_cast(half2v, hu), acc, false);
#else
  half2v a = __builtin_bit_cast(half2v, wu);
  half2v b = __builtin_bit_cast(half2v, hu);
  return acc + (float)a[0] * (float)b[0] + (float)a[1] * (float)b[1];
#endif
}

__device__ __forceinline__ float tanh_fast(float x) {
  float e = __expf(2.f * x);
  return 1.f - 2.f / (e + 1.f);
}

__device__ __forceinline__ float sigmoid_fast(float x) {
  return 1.f / (1.f + __expf(-x));
}

__device__ __forceinline__ void gload_lds16(const void* g, void* l) {
#if defined(__has_builtin) && __has_builtin(__builtin_amdgcn_global_load_lds)
  __builtin_amdgcn_global_load_lds(
      (const __attribute__((address_space(1))) void*)g,
      (__attribute__((address_space(3))) void*)l, 16, 0, 0);
#else
  *(uint4*)l = *(const uint4*)g;
#endif
}

// ---------------------------------------------------------------- prep ----
__global__ void prep_kernel(const float* __restrict__ WhhE, const float* __restrict__ WhhD,
                            const float* __restrict__ Wout,
                            unsigned* __restrict__ WhhP, unsigned short* __restrict__ WoutB) {
  int i = blockIdx.x * blockDim.x + threadIdx.x;
  int stride = gridDim.x * blockDim.x;
  // Whh pack: layout [p][d][g], d = k-pair dword 0..127, g = gate row 0..1023
  for (int idx = i; idx < 262144; idx += stride) {
    int p = idx >> 17;
    int rem = idx & 131071;
    int d = rem >> 10;
    int g = rem & 1023;
    const float* W = p ? WhhD : WhhE;
    float a = W[g * 256 + 2 * d];
    float b = W[g * 256 + 2 * d + 1];
    WhhP[idx] = (unsigned)f2h_bits(a) | ((unsigned)f2h_bits(b) << 16);
  }
  for (int idx = i; idx < 8192000; idx += stride) {
    WoutB[idx] = f2bf_bits(Wout[idx]);
  }
}

// ------------------------------------------------------------------ xg ----
// xg[m][n] = sum_e emb[tok(m)][e] * Wih[n][e],  m = p*4096 + b*128 + t (8192 rows), n = 0..1023
__global__ __launch_bounds__(256, 2) void xg_kernel(
    const int* __restrict__ x, const int* __restrict__ y,
    const float* __restrict__ enc_emb, const float* __restrict__ dec_emb,
    const float* __restrict__ Wih_enc, const float* __restrict__ Wih_dec,
    float* __restrict__ xg) {
  __shared__ float Al[64][132];
  __shared__ float Bl[64][132];
  __shared__ int tok[64];
  const int nb = blockIdx.x;     // 0..15  (n tile)
  const int mbb = blockIdx.y;    // 0..127 (m tile)
  const int m0 = mbb * 64;
  const int p = mbb >> 6;
  const int tid = threadIdx.x;

  if (tid < 64) {
    int mloc = (m0 + tid) & 4095;  // index into x/y flat [32*128]
    tok[tid] = p ? y[mloc] : x[mloc];
  }
  __syncthreads();

  const float* emb = p ? dec_emb : enc_emb;
  const float* Wih = p ? Wih_dec : Wih_enc;
  {
    int ri = tid & 63, seg = tid >> 6;  // 64 rows x 4 segments of 32 floats
    const float* er = emb + (size_t)tok[ri] * 128 + seg * 32;
    const float* wr = Wih + (size_t)(nb * 64 + ri) * 128 + seg * 32;
#pragma unroll
    for (int c = 0; c < 8; ++c) {
      *(float4*)&Al[ri][seg * 32 + c * 4] = *(const float4*)&er[c * 4];
      *(float4*)&Bl[ri][seg * 32 + c * 4] = *(const float4*)&wr[c * 4];
    }
  }
  __syncthreads();

  const int tx = tid & 15, ty = tid >> 4;
  float acc[4][4];
#pragma unroll
  for (int mm = 0; mm < 4; ++mm)
#pragma unroll
    for (int nn = 0; nn < 4; ++nn) acc[mm][nn] = 0.f;

  for (int k4 = 0; k4 < 32; ++k4) {
    float4 av[4], bv[4];
#pragma unroll
    for (int mm = 0; mm < 4; ++mm) av[mm] = *(const float4*)&Al[mm * 16 + ty][k4 * 4];
#pragma unroll
    for (int nn = 0; nn < 4; ++nn) bv[nn] = *(const float4*)&Bl[nn * 16 + tx][k4 * 4];
#pragma unroll
    for (int mm = 0; mm < 4; ++mm)
#pragma unroll
      for (int nn = 0; nn < 4; ++nn) {
        acc[mm][nn] = fmaf(av[mm].x, bv[nn].x, acc[mm][nn]);
        acc[mm][nn] = fmaf(av[mm].y, bv[nn].y, acc[mm][nn]);
        acc[mm][nn] = fmaf(av[mm].z, bv[nn].z, acc[mm][nn]);
        acc[mm][nn] = fmaf(av[mm].w, bv[nn].w, acc[mm][nn]);
      }
  }
#pragma unroll
  for (int mm = 0; mm < 4; ++mm)
#pragma unroll
    for (int nn = 0; nn < 4; ++nn)
      xg[(size_t)(m0 + mm * 16 + ty) * 1024 + nb * 64 + nn * 16 + tx] = acc[mm][nn];
}

// ---------------------------------------------------------------- lstm ----
// ROUND-1 VERBATIM (measured 601 us). One WG per batch. 1024 threads; thread t owns gate
// row g=t (q=t>>8 in {i,f,g,o}, unit j=t&255). Weight row: wqd[0..91] in VGPR/AGPR,
// WL LDS slice holds k-pairs 92..127 (36 dwords/thread, thread-private column).
__global__ __launch_bounds__(1024, 1) void lstm_kernel(
    const float* __restrict__ xg, const unsigned* __restrict__ WhhP,
    const float* __restrict__ bih_enc, const float* __restrict__ bhh_enc,
    const float* __restrict__ bih_dec, const float* __restrict__ bhh_dec,
    unsigned short* __restrict__ decO) {   // bf16 [4096][256]
  const int b = blockIdx.x;   // batch 0..31
  const int t = threadIdx.x;  // 0..1023
  const int g = t;            // gate row
  const int q = t >> 8;       // gate class 0..3 (i,f,g,o) -- wave-uniform
  const int j = t & 255;      // unit

  __shared__ __align__(16) unsigned h2[128];   // full h as f16x2 pairs (256 f16)
  __shared__ float gact[4][256];
  __shared__ unsigned WL[18 * 2048];           // [dp][g][2] : k-pairs 92..127, 147,456 B

  if (t < 128) h2[t] = 0u;
  float c_r = 0.f;  // cell state, owned by t<256 threads (unit j=t)
  __syncthreads();

  unsigned wqd[92];  // register-resident f16x2 weight row, k-pairs 0..91
  float bias_g = 0.f;

  // prefetch xg for s=0
  float xgv_n = xg[(size_t)(b << 7) * 1024 + g];

  for (int s = 0; s < 256; ++s) {
    const int p = s >> 7;
    const int tt = s & 127;

    if ((s & 127) == 0) {  // phase start: (re)load weights + bias
      const unsigned* base = WhhP + (p << 17);
#pragma unroll
      for (int d = 0; d < 92; ++d) wqd[d] = base[(d << 10) + g];
      // LDS slice: thread-private column, b64-pair layout [dp][g][2]
#pragma unroll
      for (int dd = 0; dd < 36; ++dd)
        WL[((dd >> 1) << 11) + (g << 1) + (dd & 1)] = base[((92 + dd) << 10) + g];
      bias_g = p ? (bih_dec[g] + bhh_dec[g]) : (bih_enc[g] + bhh_enc[g]);
    }

    const float xgv = xgv_n;
    if (s < 255) {  // prefetch next step's xg (independent of recurrence)
      const int sn = s + 1;
      xgv_n = xg[(size_t)(((sn >> 7) << 12) + (b << 7) + (sn & 127)) * 1024 + g];
    }

    // full-k dot: h2 reads are wave-uniform (broadcast, conflict-free)
    float a0 = 0.f, a1 = 0.f, a2 = 0.f, a3 = 0.f;
#pragma unroll
    for (int c = 0; c < 23; ++c) {
      const uint4 hv = *(const uint4*)&h2[c << 2];
      a0 = fdot2u(wqd[4 * c + 0], hv.x, a0);
      a1 = fdot2u(wqd[4 * c + 1], hv.y, a1);
      a2 = fdot2u(wqd[4 * c + 2], hv.z, a2);
      a3 = fdot2u(wqd[4 * c + 3], hv.w, a3);
    }
#pragma unroll
    for (int c = 23; c < 32; ++c) {
      const uint4 hv = *(const uint4*)&h2[c << 2];
      const int dp0 = (4 * c - 92) >> 1;  // 0,2,4,...,16
      const uint2 w01 = *(const uint2*)&WL[(dp0 << 11) + (g << 1)];
      const uint2 w23 = *(const uint2*)&WL[((dp0 + 1) << 11) + (g << 1)];
      a0 = fdot2u(w01.x, hv.x, a0);
      a1 = fdot2u(w01.y, hv.y, a1);
      a2 = fdot2u(w23.x, hv.z, a2);
      a3 = fdot2u(w23.y, hv.w, a3);
    }
    const float accf = bias_g + xgv + ((a0 + a1) + (a2 + a3));

    // activation (q wave-uniform: no divergence)
    const float act = (q == 2) ? tanh_fast(accf) : sigmoid_fast(accf);
    gact[q][j] = act;
    __syncthreads();

    if (t < 256) {  // unit j=t update (waves 0..3 fully active -> shfl safe)
      const float iv = gact[0][t];
      const float fv = gact[1][t];
      const float gv = gact[2][t];
      const float ov = gact[3][t];
      c_r = fv * c_r + iv * gv;
      const float hh = ov * tanh_fast(c_r);
      if (p) decO[(size_t)((b << 7) + tt) * 256 + t] = f2bf_bits(hh);
      const float hn = __shfl_down(hh, 1, 64);
      if (!(t & 1))
        h2[t >> 1] = (unsigned)f2h_bits(hh) | ((unsigned)f2h_bits(hn) << 16);
    }
    __syncthreads();  // h2 update visible before next step's dot
  }
}

// ---------------------------------------------------------------- proj ----
// out[m][n] = sum_k A[m][k]*Bw[n][k] + bias[n];  M=4096 N=32000 K=256, bf16 MFMA.
// N-strip persistent: WG owns 64 vocab rows. B staged once; B-frags hoisted to regs
// (2 N-tiles x 8 k-steps = 16 bf16x8 = 64 VGPR). M-loop: 128 chunks x 32 rows,
// double-buffered A (2x16 KB), counted vmcnt(8) so output stores stay in flight.
// Swizzle: LDS[m][k8] holds global k-slot k8^(m&15); readers use the same involution.
__global__ __launch_bounds__(256, 2) void proj_kernel(
    const unsigned short* __restrict__ A,   // decO bf16 [4096][256]
    const unsigned short* __restrict__ Bw,  // WoutB bf16 [32000][256]
    const float* __restrict__ bias, float* __restrict__ out) {
  __shared__ unsigned short Bl[64 * 256];       // 32 KB
  __shared__ unsigned short Al[2][32 * 256];    // 2 x 16 KB
  const int n0 = blockIdx.x << 6;     // 0..499 -> vocab row base
  const int tid = threadIdx.x;
  const int wv = tid >> 6, ln = tid & 63;
  const int wm = wv & 1;              // M-half of the 32-row chunk (16 rows)
  const int wn = wv >> 1;             // N-half of the 64-row strip (32 cols)
  const int l16 = ln & 15, lq = ln >> 4;

  // stage B strip (once): slot st -> (n = st>>5, k8 = st&31), source k8 ^ (n&15)
#pragma unroll
  for (int it = 0; it < 8; ++it) {
    int st = it * 256 + tid;
    int m = st >> 5, k8 = st & 31;
    gload_lds16(Bw + (size_t)(n0 + m) * 256 + ((k8 ^ (m & 15)) << 3), &Bl[st << 3]);
  }
  // stage A chunk 0
#pragma unroll
  for (int it = 0; it < 4; ++it) {
    int st = it * 256 + tid;
    int m = st >> 5, k8 = st & 31;
    gload_lds16(A + (size_t)m * 256 + ((k8 ^ (m & 15)) << 3), &Al[0][st << 3]);
  }
  asm volatile("s_waitcnt vmcnt(0)" ::: "memory");
  __syncthreads();

  // hoist B fragments into registers: bfr[nt][ks], reused for all 128 chunks
  bf16x8 bfr[2][8];
#pragma unroll
  for (int nt = 0; nt < 2; ++nt)
#pragma unroll
    for (int ks = 0; ks < 8; ++ks) {
      int n = (wn << 5) + (nt << 4) + l16;
      int k8 = (ks << 2) + lq;
      bfr[nt][ks] = *(const bf16x8*)&Bl[((n << 5) | (k8 ^ (n & 15))) << 3];
    }
  const int gc0 = n0 + (wn << 5) + l16;
  const float bs0 = bias[gc0];
  const float bs1 = bias[gc0 + 16];

  for (int c = 0; c < 128; ++c) {
    const int cur = c & 1;
    if (c < 127) {  // issue next A chunk (4 gload_lds) before compute
      const unsigned short* Ab = A + (size_t)(c + 1) * (32 * 256);
#pragma unroll
      for (int it = 0; it < 4; ++it) {
        int st = it * 256 + tid;
        int m = st >> 5, k8 = st & 31;
        gload_lds16(Ab + (size_t)m * 256 + ((k8 ^ (m & 15)) << 3), &Al[cur ^ 1][st << 3]);
      }
    }

    f32x4 acc0 = {}, acc1 = {};
#pragma unroll
    for (int ks = 0; ks < 8; ++ks) {
      const int k8 = (ks << 2) + lq;
      const int m = (wm << 4) + l16;
      const bf16x8 af = *(const bf16x8*)&Al[cur][((m << 5) | (k8 ^ (m & 15))) << 3];
      acc0 = __builtin_amdgcn_mfma_f32_16x16x32_bf16(af, bfr[0][ks], acc0, 0, 0, 0);
      acc1 = __builtin_amdgcn_mfma_f32_16x16x32_bf16(af, bfr[1][ks], acc1, 0, 0, 0);
    }

    // write 8 f32 (two 16-col groups x 4 rows); these stay in flight past vmcnt(8)
    const int grow0 = (c << 5) + (wm << 4) + (lq << 2);
#pragma unroll
    for (int rr = 0; rr < 4; ++rr) {
      out[(size_t)(grow0 + rr) * 32000 + gc0] = acc0[rr] + bs0;
      out[(size_t)(grow0 + rr) * 32000 + gc0 + 16] = acc1[rr] + bs1;
    }

    // drain only the 4 A-loads (older than the 8 stores); stores may stay outstanding
    asm volatile("s_waitcnt vmcnt(8)" ::: "memory");
    __syncthreads();
  }
}

// -------------------------------------------------------------- launch ----
extern "C" void kernel_launch(void* const* d_in, const int* in_sizes, int n_in,
                              void* d_out, int out_size, void* d_ws, size_t ws_size,
                              hipStream_t stream) {
  const int* x = (const int*)d_in[0];
  const int* y = (const int*)d_in[1];
  const float* enc_emb = (const float*)d_in[2];
  const float* dec_emb = (const float*)d_in[3];
  const float* Wih_enc = (const float*)d_in[4];
  const float* Whh_enc = (const float*)d_in[5];
  const float* bih_enc = (const float*)d_in[6];
  const float* bhh_enc = (const float*)d_in[7];
  const float* Wih_dec = (const float*)d_in[8];
  const float* Whh_dec = (const float*)d_in[9];
  const float* bih_dec = (const float*)d_in[10];
  const float* bhh_dec = (const float*)d_in[11];
  const float* W_out = (const float*)d_in[12];
  const float* b_out = (const float*)d_in[13];

  char* ws = (char*)d_ws;
  float* xg = (float*)ws;                                       // 33,554,432
  unsigned* WhhP = (unsigned*)(ws + 33554432);                  //  1,048,576
  unsigned short* WoutB = (unsigned short*)(ws + 34603008);     // 16,384,000
  unsigned short* decO = (unsigned short*)(ws + 50987008);      //  2,097,152
  if (ws_size < 57344000) return;  // insufficient workspace (would corrupt)

  prep_kernel<<<4096, 256, 0, stream>>>(Whh_enc, Whh_dec, W_out, WhhP, WoutB);
  xg_kernel<<<dim3(16, 128), 256, 0, stream>>>(x, y, enc_emb, dec_emb, Wih_enc, Wih_dec, xg);
  lstm_kernel<<<32, 1024, 0, stream>>>(xg, WhhP, bih_enc, bhh_enc, bih_dec, bhh_dec, decO);
  proj_kernel<<<500, 256, 0, stream>>>(decO, WoutB, b_out, (float*)d_out);
}